// Round 1
// baseline (59.730 us; speedup 1.0000x reference)
//
#include <hip/hip_runtime.h>

#define EPS 1e-8f

// ---------------------------------------------------------------------------
// Pass 1: for each (b,f) chain and each time-chunk c, run the EMA recurrence
// with carry-in = 0 and store only the chunk-end value S_c = local scan end.
// By linearity:  true_carry_out(c) = carry_in(c) * (1-a)^L + S_c.
// ---------------------------------------------------------------------------
__global__ void fns_pass1(const float* __restrict__ mag,
                          const float* __restrict__ alpha,
                          float* __restrict__ S,   // [C][BF]
                          int B, int T, int F, int L, int C) {
    int g = blockIdx.x * blockDim.x + threadIdx.x;
    int BF = B * F;
    int total = BF * C;
    if (g >= total) return;
    int bf = g % BF;
    int c  = g / BF;
    int b = bf / F;
    int f = bf - b * F;

    float a = 1.0f / (1.0f + expf(-alpha[f]));

    int t0 = c * L;
    int t1 = min(t0 + L, T);
    const float* p = mag + (size_t)b * T * F + f;

    float local = 0.0f;
    for (int t = t0; t < t1; ++t) {
        float m  = p[(size_t)t * F];
        float pw = m * m;
        local = local * (1.0f - a) + pw * a;   // exact reference form
    }
    S[(size_t)c * BF + bf] = local;
}

// ---------------------------------------------------------------------------
// Pass 2: per (b,f) chain, sequentially propagate carries across the C chunk
// summaries. Overwrites S[c][bf] with the carry-IN for chunk c.
// ---------------------------------------------------------------------------
__global__ void fns_pass2(const float* __restrict__ s0,
                          const float* __restrict__ alpha,
                          float* __restrict__ S,   // in: S_c, out: carry_in(c)
                          int B, int F, int L, int C) {
    int bf = blockIdx.x * blockDim.x + threadIdx.x;
    int BF = B * F;
    if (bf >= BF) return;
    int b = bf / F;
    int f = bf - b * F;

    float a = 1.0f / (1.0f + expf(-alpha[f]));
    float decay = powf(1.0f - a, (float)L);

    float carry = s0[bf];
    for (int c = 0; c < C; ++c) {
        size_t idx = (size_t)c * BF + bf;
        float Sc = S[idx];
        S[idx] = carry;                 // carry-in for chunk c
        carry = carry * decay + Sc;     // carry-out -> carry-in for c+1
    }
}

// ---------------------------------------------------------------------------
// Pass 3: re-run the recurrence per (b,f,chunk) starting from the exact
// carry-in, compute the normalized output. mag re-read should be L3-warm.
// ---------------------------------------------------------------------------
__global__ void fns_pass3(const float* __restrict__ mag,
                          const float* __restrict__ alpha,
                          const float* __restrict__ weights,
                          const float* __restrict__ bias,
                          const float* __restrict__ carryin, // [C][BF]
                          float* __restrict__ out,
                          int B, int T, int F, int L, int C) {
    int g = blockIdx.x * blockDim.x + threadIdx.x;
    int BF = B * F;
    int total = BF * C;
    if (g >= total) return;
    int bf = g % BF;
    int c  = g / BF;
    int b = bf / F;
    int f = bf - b * F;

    float a  = 1.0f / (1.0f + expf(-alpha[f]));
    float w  = weights[f];
    float bi = bias[f];

    float carry = carryin[(size_t)c * BF + bf];

    int t0 = c * L;
    int t1 = min(t0 + L, T);
    const float* p = mag + (size_t)b * T * F + f;
    float*       o = out + (size_t)b * T * F + f;

    for (int t = t0; t < t1; ++t) {
        float m  = p[(size_t)t * F];
        float pw = m * m;
        carry = carry * (1.0f - a) + pw * a;
        o[(size_t)t * F] = m / (sqrtf(carry) + EPS) * w + bi;
    }
}

// ---------------------------------------------------------------------------
// Fallback: one thread per (b,f) chain, full sequential scan (used only if
// the workspace is too small for the chunked path).
// ---------------------------------------------------------------------------
__global__ void fns_fallback(const float* __restrict__ mag,
                             const float* __restrict__ s0,
                             const float* __restrict__ weights,
                             const float* __restrict__ bias,
                             const float* __restrict__ alpha,
                             float* __restrict__ out,
                             int B, int T, int F) {
    int bf = blockIdx.x * blockDim.x + threadIdx.x;
    int BF = B * F;
    if (bf >= BF) return;
    int b = bf / F;
    int f = bf - b * F;

    float a  = 1.0f / (1.0f + expf(-alpha[f]));
    float w  = weights[f];
    float bi = bias[f];

    float carry = s0[bf];
    const float* p = mag + (size_t)b * T * F + f;
    float*       o = out + (size_t)b * T * F + f;

    for (int t = 0; t < T; ++t) {
        float m  = p[(size_t)t * F];
        float pw = m * m;
        carry = carry * (1.0f - a) + pw * a;
        o[(size_t)t * F] = m / (sqrtf(carry) + EPS) * w + bi;
    }
}

extern "C" void kernel_launch(void* const* d_in, const int* in_sizes, int n_in,
                              void* d_out, int out_size, void* d_ws, size_t ws_size,
                              hipStream_t stream) {
    const float* mag     = (const float*)d_in[0];
    const float* s0      = (const float*)d_in[1];
    const float* weights = (const float*)d_in[2];
    const float* bias    = (const float*)d_in[3];
    const float* alpha   = (const float*)d_in[4];
    float* out = (float*)d_out;

    int F  = in_sizes[4];          // alpha is [1, F]
    int BF = in_sizes[1];          // s is [B, F]
    int B  = BF / F;
    int T  = in_sizes[0] / BF;     // mag is [B, T, F]

    const int C = 20;              // time chunks
    int L = (T + C - 1) / C;       // chunk length (50 for T=1000)

    size_t ws_needed = (size_t)C * BF * sizeof(float);
    if (ws_size < ws_needed) {
        // Fallback: low-parallelism but correct.
        int threads = 256;
        int blocks  = (BF + threads - 1) / threads;
        fns_fallback<<<blocks, threads, 0, stream>>>(mag, s0, weights, bias,
                                                     alpha, out, B, T, F);
        return;
    }

    float* S = (float*)d_ws;       // [C][BF]

    int threads = 256;
    int n13     = BF * C;
    int blocks13 = (n13 + threads - 1) / threads;
    int blocks2  = (BF + threads - 1) / threads;

    fns_pass1<<<blocks13, threads, 0, stream>>>(mag, alpha, S, B, T, F, L, C);
    fns_pass2<<<blocks2,  threads, 0, stream>>>(s0, alpha, S, B, F, L, C);
    fns_pass3<<<blocks13, threads, 0, stream>>>(mag, alpha, weights, bias, S,
                                                out, B, T, F, L, C);
}